// Round 20
// baseline (192.867 us; speedup 1.0000x reference)
//
#include <hip/hip_runtime.h>
#include <hip/hip_bf16.h>

#define B_ 2
#define S_ 1024
#define D_ 1024
#define H_ 16
#define K_ 33
#define DH 64
#define SCALE 0.07216878364870322f  // 1/sqrt(3*64)
#define LOG2E 1.4426950408889634f
#define SCALEL (SCALE * LOG2E)
#define FXS 32768.0f
#define FXI (1.0f / 32768.0f)

typedef __attribute__((ext_vector_type(8))) short bf16x8;
typedef __attribute__((ext_vector_type(4))) float f32x4;

// ---------- dtype helpers ----------
__device__ __forceinline__ float b2f(unsigned short u) {
    return __uint_as_float(((unsigned int)u) << 16);
}
__device__ __forceinline__ unsigned short f2b(float f) {  // RNE
    unsigned int u = __float_as_uint(f);
    u += 0x7FFFu + ((u >> 16) & 1u);
    return (unsigned short)(u >> 16);
}
__device__ __forceinline__ float ldf(const void* p, int i, int f32) {
    return f32 ? ((const float*)p)[i] : b2f(((const unsigned short*)p)[i]);
}
__device__ __forceinline__ float4 ldf4(const void* p, int i, int f32) {  // i % 4 == 0
    if (f32) return *(const float4*)((const float*)p + i);
    ushort4 u = *(const ushort4*)((const unsigned short*)p + i);
    return make_float4(b2f(u.x), b2f(u.y), b2f(u.z), b2f(u.w));
}
__device__ __forceinline__ float4 ldb4(const unsigned short* p, int i) {  // bf16 buffer
    ushort4 u = *(const ushort4*)(p + i);
    return make_float4(b2f(u.x), b2f(u.y), b2f(u.z), b2f(u.w));
}
__device__ __forceinline__ int sniff_f32(const void* hidden) {
    __shared__ int cnt;
    if (threadIdx.x == 0) cnt = 0;
    __syncthreads();
    const unsigned short* hu = (const unsigned short*)hidden;
    int c = 0;
    for (int i = threadIdx.x; i < 2048; i += 256) {
        int e = (hu[i] >> 7) & 0xFF;
        if (e >= 0x8E) c++;
    }
    if (c) atomicAdd(&cnt, c);
    __syncthreads();
    return (cnt >= 8) ? 1 : 0;
}

// ---------------- fused setup: pos_pack (blocks 0..2047), w_pack (2048..3071), prep (3072) ----------------
__global__ __launch_bounds__(256) void setup_fused(const void* __restrict__ hidden,
                                                   const void* __restrict__ mask,
                                                   const int* __restrict__ pos,
                                                   const void* __restrict__ W0,
                                                   const void* __restrict__ W1,
                                                   const void* __restrict__ W2,
                                                   const void* __restrict__ W3,
                                                   int* __restrict__ flags,
                                                   float* __restrict__ mflag,
                                                   unsigned char* __restrict__ pos8,
                                                   unsigned short* __restrict__ T0,
                                                   unsigned short* __restrict__ T1,
                                                   unsigned short* __restrict__ T2,
                                                   unsigned short* __restrict__ T3) {
    const int bid = blockIdx.x;
    const int t = threadIdx.x;
    if (bid < 2048) {
        int i = bid * 256 + t;
        if (i < (B_ * S_ * S_) / 4) {
            int4 p = *(const int4*)&pos[i * 4];
            uchar4 o;
            o.x = (unsigned char)min(max(p.x, 0), K_ - 1);
            o.y = (unsigned char)min(max(p.y, 0), K_ - 1);
            o.z = (unsigned char)min(max(p.z, 0), K_ - 1);
            o.w = (unsigned char)min(max(p.w, 0), K_ - 1);
            *(uchar4*)&pos8[i * 4] = o;
        }
        return;
    }
    if (bid < 3072) {
        const int f32u = sniff_f32(hidden);
        __shared__ unsigned short tl[64][66];
        int r = bid - 2048;
        int z = r >> 8;
        int wy = (r & 255) >> 4, wx = r & 15;
        const void* W = z == 0 ? W0 : (z == 1 ? W1 : (z == 2 ? W2 : W3));
        unsigned short* T = z == 0 ? T0 : (z == 1 ? T1 : (z == 2 ? T2 : T3));
        const int k0 = wy * 64, n0 = wx * 64;
        {
            int kr = t >> 2, nc = (t & 3) * 16;
#pragma unroll
            for (int u = 0; u < 4; ++u) {
                float4 v = ldf4(W, (k0 + kr) * 1024 + n0 + nc + u * 4, f32u);
                tl[kr][nc + u * 4 + 0] = f2b(v.x);
                tl[kr][nc + u * 4 + 1] = f2b(v.y);
                tl[kr][nc + u * 4 + 2] = f2b(v.z);
                tl[kr][nc + u * 4 + 3] = f2b(v.w);
            }
        }
        __syncthreads();
        {
            int nr = t >> 2, kc = (t & 3) * 16;
            unsigned short o[16];
#pragma unroll
            for (int u = 0; u < 16; ++u) o[u] = tl[kc + u][nr];
#pragma unroll
            for (int u = 0; u < 4; ++u)
                *(ushort4*)&T[(n0 + nr) * 1024 + k0 + kc + u * 4] = *(ushort4*)&o[u * 4];
        }
        return;
    }
    // ---- prep role ----
    {
        __shared__ int mev[6];
        const int f32u = sniff_f32(hidden);
        if (t < 6) mev[t] = 0;
        __syncthreads();
        const unsigned char* mb = (const unsigned char*)mask;
        int e_bf = 0, e_f32 = 0, e_f64 = 0, e_f16 = 0, e_u8 = 0;
        for (int p = t; p < 2048; p += 256) {
            unsigned char v = mb[p];
            if ((p & 7) == 6 && v == 0xF0) e_f64 = 1;
            if ((p & 3) == 1 && v == 0x3F) e_bf = 1;
            if ((p & 3) == 3 && v == 0x3F) e_f32 = 1;
            if ((p & 1) == 1 && v == 0x3C) e_f16 = 1;
            if ((p & 3) != 0 && v != 0) e_u8 = 1;
        }
        if (e_f64) atomicOr(&mev[5], 1);
        if (e_bf)  atomicOr(&mev[3], 1);
        if (e_f32) atomicOr(&mev[2], 1);
        if (e_f16) atomicOr(&mev[4], 1);
        if (e_u8)  atomicOr(&mev[1], 1);
        __syncthreads();
        const int mm = mev[5] ? 5 : (mev[3] ? 3 : (mev[2] ? 2 : (mev[4] ? 4 : (mev[1] ? 1 : 0))));
        if (t == 0) { flags[0] = f32u; flags[2] = mm; }
        for (int j = t; j < B_ * S_; j += 256) {
            int m;
            if (mm == 5)      m = (((const double*)mask)[j] != 0.0);
            else if (mm == 3 || mm == 4) m = (((const unsigned short*)mask)[j] != 0);
            else if (mm == 2) m = (((const float*)mask)[j] != 0.f);
            else if (mm == 1) m = (mb[j] != 0);
            else              m = (((const int*)mask)[j] != 0);
            mflag[j] = m ? 1.f : 0.f;
        }
    }
}

// ---------------- standalone fallbacks (small-ws path) ----------------
__global__ __launch_bounds__(256) void prep(const void* __restrict__ hidden,
                                            const void* __restrict__ mask,
                                            int* __restrict__ flags,
                                            float* __restrict__ mflag) {
    __shared__ int mev[6];
    const int t = threadIdx.x;
    const int f32u = sniff_f32(hidden);
    if (t < 6) mev[t] = 0;
    __syncthreads();
    const unsigned char* mb = (const unsigned char*)mask;
    int e_bf = 0, e_f32 = 0, e_f64 = 0, e_f16 = 0, e_u8 = 0;
    for (int p = t; p < 2048; p += 256) {
        unsigned char v = mb[p];
        if ((p & 7) == 6 && v == 0xF0) e_f64 = 1;
        if ((p & 3) == 1 && v == 0x3F) e_bf = 1;
        if ((p & 3) == 3 && v == 0x3F) e_f32 = 1;
        if ((p & 1) == 1 && v == 0x3C) e_f16 = 1;
        if ((p & 3) != 0 && v != 0) e_u8 = 1;
    }
    if (e_f64) atomicOr(&mev[5], 1);
    if (e_bf)  atomicOr(&mev[3], 1);
    if (e_f32) atomicOr(&mev[2], 1);
    if (e_f16) atomicOr(&mev[4], 1);
    if (e_u8)  atomicOr(&mev[1], 1);
    __syncthreads();
    const int mm = mev[5] ? 5 : (mev[3] ? 3 : (mev[2] ? 2 : (mev[4] ? 4 : (mev[1] ? 1 : 0))));
    if (t == 0) { flags[0] = f32u; flags[2] = mm; }
    for (int j = t; j < B_ * S_; j += 256) {
        int m;
        if (mm == 5)      m = (((const double*)mask)[j] != 0.0);
        else if (mm == 3 || mm == 4) m = (((const unsigned short*)mask)[j] != 0);
        else if (mm == 2) m = (((const float*)mask)[j] != 0.f);
        else if (mm == 1) m = (mb[j] != 0);
        else              m = (((const int*)mask)[j] != 0);
        mflag[j] = m ? 1.f : 0.f;
    }
}

__global__ __launch_bounds__(256) void pos_pack(const int* __restrict__ pos,
                                                unsigned char* __restrict__ pos8) {
    int i = blockIdx.x * 256 + threadIdx.x;
    if (i >= (B_ * S_ * S_) / 4) return;
    int4 p = *(const int4*)&pos[i * 4];
    uchar4 o;
    o.x = (unsigned char)min(max(p.x, 0), K_ - 1);
    o.y = (unsigned char)min(max(p.y, 0), K_ - 1);
    o.z = (unsigned char)min(max(p.z, 0), K_ - 1);
    o.w = (unsigned char)min(max(p.w, 0), K_ - 1);
    *(uchar4*)&pos8[i * 4] = o;
}

// ---------------- MFMA GEMM v5: 128x64 tile, 256 thr = 4 waves, BK=32, reg-prefetch ----------------
__global__ __launch_bounds__(256, 3) void gemm_qkv_mfma(const void* __restrict__ X,
                                                        const void* __restrict__ W0,
                                                        const void* __restrict__ W1,
                                                        const void* __restrict__ W2,
                                                        const unsigned short* __restrict__ T0,
                                                        const unsigned short* __restrict__ T1,
                                                        const unsigned short* __restrict__ T2,
                                                        const void* __restrict__ b0,
                                                        const void* __restrict__ b1,
                                                        const void* __restrict__ b2,
                                                        const int* __restrict__ flags, int useT,
                                                        unsigned short* __restrict__ q,
                                                        unsigned short* __restrict__ kk_,
                                                        unsigned short* __restrict__ v) {
    __shared__ unsigned short Asl[128][40];
    __shared__ unsigned short Bsl[64][40];
    const int f32u = flags[0];
    const int z = blockIdx.z;
    const void* W = z == 0 ? W0 : (z == 1 ? W1 : W2);
    const unsigned short* WT = z == 0 ? T0 : (z == 1 ? T1 : T2);
    const void* bias = z == 0 ? b0 : (z == 1 ? b1 : b2);
    unsigned short* outp = z == 0 ? q : (z == 1 ? kk_ : v);
    const int m0 = blockIdx.y * 128, n0 = blockIdx.x * 64;
    const int t = threadIdx.x;
    const int w = t >> 6, lane = t & 63;
    const int wr = w >> 1, wc = w & 1;
    const int lm = lane & 15, lg = lane >> 4;

    const int am = t >> 1, ac16 = (t & 1) * 16;
    const int bn = t >> 2, bk8 = (t & 3) * 8;
    const int fbn = t & 63, fbkq = (t >> 6) * 8;

    f32x4 acc[4][2] = {};
    float4 pa[4];
    ushort4 tb0, tb1;
    float pbx[8];

    {
        int base = (m0 + am) * 1024 + ac16;
#pragma unroll
        for (int u = 0; u < 4; ++u) pa[u] = ldf4(X, base + u * 4, f32u);
        if (useT) {
            const ushort4* s = (const ushort4*)&WT[(n0 + bn) * 1024 + bk8];
            tb0 = s[0]; tb1 = s[1];
        } else {
#pragma unroll
            for (int qi = 0; qi < 8; ++qi)
                pbx[qi] = ldf(W, (fbkq + qi) * 1024 + n0 + fbn, f32u);
        }
    }

    for (int k0 = 0; k0 < 1024; k0 += 32) {
        {
#pragma unroll
            for (int u = 0; u < 4; ++u) {
                ushort4 uv = {f2b(pa[u].x), f2b(pa[u].y), f2b(pa[u].z), f2b(pa[u].w)};
                *(ushort4*)&Asl[am][ac16 + u * 4] = uv;
            }
            if (useT) {
                *(ushort4*)&Bsl[bn][bk8] = tb0;
                *(ushort4*)&Bsl[bn][bk8 + 4] = tb1;
            } else {
#pragma unroll
                for (int qi = 0; qi < 8; qi += 2) {
                    unsigned int pk = (unsigned int)f2b(pbx[qi]) |
                                      ((unsigned int)f2b(pbx[qi + 1]) << 16);
                    *(unsigned int*)&Bsl[fbn][fbkq + qi] = pk;
                }
            }
        }
        __syncthreads();
        if (k0 + 32 < 1024) {
            int kn = k0 + 32;
            int base = (m0 + am) * 1024 + kn + ac16;
#pragma unroll
            for (int u = 0; u < 4; ++u) pa[u] = ldf4(X, base + u * 4, f32u);
            if (useT) {
                const ushort4* s = (const ushort4*)&WT[(n0 + bn) * 1024 + kn + bk8];
                tb0 = s[0]; tb1 = s[1];
            } else {
#pragma unroll
                for (int qi = 0; qi < 8; ++qi)
                    pbx[qi] = ldf(W, (kn + fbkq + qi) * 1024 + n0 + fbn, f32u);
            }
        }
        bf16x8 af[4], bfr[2];
#pragma unroll
        for (int mi = 0; mi < 4; ++mi)
            af[mi] = *(const bf16x8*)&Asl[wr * 64 + mi * 16 + lm][lg * 8];
#pragma unroll
        for (int nj = 0; nj < 2; ++nj)
            bfr[nj] = *(const bf16x8*)&Bsl[wc * 32 + nj * 16 + lm][lg * 8];
#pragma unroll
        for (int mi = 0; mi < 4; ++mi)
#pragma unroll
            for (int nj = 0; nj < 2; ++nj)
                acc[mi][nj] = __builtin_amdgcn_mfma_f32_16x16x32_bf16(af[mi], bfr[nj],
                                                                      acc[mi][nj], 0, 0, 0);
        __syncthreads();
    }
#pragma unroll
    for (int nj = 0; nj < 2; ++nj) {
        int n = n0 + wc * 32 + nj * 16 + lm;
        float bv = ldf(bias, n, f32u);
        int hh = n >> 6, dd = n & 63;
#pragma unroll
        for (int mi = 0; mi < 4; ++mi) {
#pragma unroll
            for (int r = 0; r < 4; ++r) {
                int m = m0 + wr * 64 + mi * 16 + lg * 4 + r;
                int bb = m >> 10, ii = m & 1023;
                outp[((bb * H_ + hh) * S_ + ii) * DH + dd] = f2b(acc[mi][nj][r] + bv);
            }
        }
    }
}

// ---------------- MFMA GEMM v5: ctx(bf16) @ Wo + bo -> f32 d_out, 128x64 tile ----------------
__global__ __launch_bounds__(256, 3) void gemm_out_mfma(const unsigned short* __restrict__ X,
                                                        const void* __restrict__ W,
                                                        const unsigned short* __restrict__ WT,
                                                        const void* __restrict__ bias,
                                                        const int* __restrict__ flags, int useT,
                                                        float* __restrict__ out) {
    __shared__ unsigned short Asl[128][40];
    __shared__ unsigned short Bsl[64][40];
    const int f32u = flags[0];
    const int m0 = blockIdx.y * 128, n0 = blockIdx.x * 64;
    const int t = threadIdx.x;
    const int w = t >> 6, lane = t & 63;
    const int wr = w >> 1, wc = w & 1;
    const int lm = lane & 15, lg = lane >> 4;

    const int am = t >> 1, ac16 = (t & 1) * 16;
    const int bn = t >> 2, bk8 = (t & 3) * 8;
    const int fbn = t & 63, fbkq = (t >> 6) * 8;

    f32x4 acc[4][2] = {};
    ushort4 pa[4];
    ushort4 tb0, tb1;
    float pbx[8];

    {
        const ushort4* src = (const ushort4*)&X[(m0 + am) * 1024 + ac16];
#pragma unroll
        for (int u = 0; u < 4; ++u) pa[u] = src[u];
        if (useT) {
            const ushort4* s = (const ushort4*)&WT[(n0 + bn) * 1024 + bk8];
            tb0 = s[0]; tb1 = s[1];
        } else {
#pragma unroll
            for (int qi = 0; qi < 8; ++qi)
                pbx[qi] = ldf(W, (fbkq + qi) * 1024 + n0 + fbn, f32u);
        }
    }

    for (int k0 = 0; k0 < 1024; k0 += 32) {
        {
#pragma unroll
            for (int u = 0; u < 4; ++u) *(ushort4*)&Asl[am][ac16 + u * 4] = pa[u];
            if (useT) {
                *(ushort4*)&Bsl[bn][bk8] = tb0;
                *(ushort4*)&Bsl[bn][bk8 + 4] = tb1;
            } else {
#pragma unroll
                for (int qi = 0; qi < 8; qi += 2) {
                    unsigned int pk = (unsigned int)f2b(pbx[qi]) |
                                      ((unsigned int)f2b(pbx[qi + 1]) << 16);
                    *(unsigned int*)&Bsl[fbn][fbkq + qi] = pk;
                }
            }
        }
        __syncthreads();
        if (k0 + 32 < 1024) {
            int kn = k0 + 32;
            const ushort4* src = (const ushort4*)&X[(m0 + am) * 1024 + kn + ac16];
#pragma unroll
            for (int u = 0; u < 4; ++u) pa[u] = src[u];
            if (useT) {
                const ushort4* s = (const ushort4*)&WT[(n0 + bn) * 1024 + kn + bk8];
                tb0 = s[0]; tb1 = s[1];
            } else {
#pragma unroll
                for (int qi = 0; qi < 8; ++qi)
                    pbx[qi] = ldf(W, (kn + fbkq + qi) * 1024 + n0 + fbn, f32u);
            }
        }
        bf16x8 af[4], bfr[2];
#pragma unroll
        for (int mi = 0; mi < 4; ++mi)
            af[mi] = *(const bf16x8*)&Asl[wr * 64 + mi * 16 + lm][lg * 8];
#pragma unroll
        for (int nj = 0; nj < 2; ++nj)
            bfr[nj] = *(const bf16x8*)&Bsl[wc * 32 + nj * 16 + lm][lg * 8];
#pragma unroll
        for (int mi = 0; mi < 4; ++mi)
#pragma unroll
            for (int nj = 0; nj < 2; ++nj)
                acc[mi][nj] = __builtin_amdgcn_mfma_f32_16x16x32_bf16(af[mi], bfr[nj],
                                                                      acc[mi][nj], 0, 0, 0);
        __syncthreads();
    }
#pragma unroll
    for (int nj = 0; nj < 2; ++nj) {
        int n = n0 + wc * 32 + nj * 16 + lm;
        float bv = ldf(bias, n, f32u);
#pragma unroll
        for (int mi = 0; mi < 4; ++mi) {
#pragma unroll
            for (int r = 0; r < 4; ++r) {
                int m = m0 + wr * 64 + mi * 16 + lg * 4 + r;
                out[m * 1024 + n] = acc[mi][nj][r] + bv;
            }
        }
    }
}

// ---------------- fused rel kernels: z=0 -> p2c, z=1 -> c2p (outputs pre-scaled by log2e) ----------------
__global__ __launch_bounds__(256) void rel_fused(const unsigned short* __restrict__ kws,
                                                 const unsigned short* __restrict__ qws,
                                                 const void* __restrict__ relq,
                                                 const void* __restrict__ relk,
                                                 const int* __restrict__ flags,
                                                 unsigned short* __restrict__ p2c,
                                                 unsigned short* __restrict__ c2p) {
    __shared__ float xt[64][68];
    __shared__ float rr[33][68];
    const int f32u = flags[0];
    const int bh = blockIdx.y, h = bh & 15;
    const int x0 = blockIdx.x * 64;
    const int t = threadIdx.x;
    if (blockIdx.z == 0) {
#pragma unroll
        for (int qq = 0; qq < 4; ++qq) {
            int idx = t + 256 * qq;
            int j = idx >> 4, d4 = idx & 15;
            *(float4*)&xt[j][d4 * 4] = ldb4(kws, (bh * S_ + x0 + j) * DH + d4 * 4);
        }
        for (int idx = t; idx < 33 * 16; idx += 256) {
            int k = idx >> 4, d4 = idx & 15;
            *(float4*)&rr[k][d4 * 4] = ldf4(relq, (h * K_ + k) * DH + d4 * 4, f32u);
        }
        __syncthreads();
        for (int o = t; o < 33 * 64; o += 256) {
            int k = o >> 6, j = o & 63;
            float s = 0.f;
#pragma unroll
            for (int d4 = 0; d4 < 16; ++d4) {
                float4 a = *(const float4*)&rr[k][d4 * 4];
                float4 b = *(const float4*)&xt[j][d4 * 4];
                s += a.x * b.x + a.y * b.y + a.z * b.z + a.w * b.w;
            }
            p2c[(bh * K_ + k) * S_ + x0 + j] = f2b(s * SCALEL);
        }
    } else {
#pragma unroll
        for (int qq = 0; qq < 4; ++qq) {
            int idx = t + 256 * qq;
            int i = idx >> 4, d4 = idx & 15;
            *(float4*)&xt[i][d4 * 4] = ldb4(qws, (bh * S_ + x0 + i) * DH + d4 * 4);
        }
        for (int idx = t; idx < 33 * 16; idx += 256) {
            int k = idx >> 4, d4 = idx & 15;
            *(float4*)&rr[k][d4 * 4] = ldf4(relk, (h * K_ + k) * DH + d4 * 4, f32u);
        }
        __syncthreads();
        for (int o = t; o < 64 * 33; o += 256) {
            int i = o / 33, k = o % 33;
            float s = 0.f;
#pragma unroll
            for (int d4 = 0; d4 < 16; ++d4) {
                float4 a = *(const float4*)&xt[i][d4 * 4];
                float4 b = *(const float4*)&rr[k][d4 * 4];
                s += a.x * b.x + a.y * b.y + a.z * b.z + a.w * b.w;
            }
            c2p[(bh * S_ + x0 + i) * K_ + k] = f2b(s * SCALEL);
        }
    }
}

// ---------------- MFMA attention v12: 16-row x 64-col micro-blocks, 2048 blocks, 19.8KB LDS ----------------
#define PS_OFF   0            // Ps [16][64] bf16 swizzled, pitch 128B (2048)
#define VT_OFF   2048         // V^T chunk staging [64][72] pitch 144B (9216)
#define P2CS_OFF 2048         // p2c strip [33][64] bf16, pitch 132B (4356, shares VT)
#define C2P_OFF  11264        // [16][34] bf16 (1088)
#define AG_OFF   12352        // [16][34] u32 (2176)
#define RV_OFF   14528        // [33][64] bf16 (4224)
#define MF_OFF   18752        // u8[1024]
#define ATTN_LDS 19776

__device__ __forceinline__ int ps_addr(int il, int jc) {  // il 0..15, jc 0..63
    return PS_OFF + il * 128 +
           ((jc * 2) ^ ((((il >> 2) & 3) << 5) ^ ((il & 3) << 4)));
}

__global__ __launch_bounds__(256, 6) void attn_mfma(const unsigned short* __restrict__ qws,
                                                    const unsigned short* __restrict__ kws,
                                                    const unsigned short* __restrict__ vws,
                                                    const unsigned short* __restrict__ p2c,
                                                    const unsigned short* __restrict__ c2p,
                                                    const float* __restrict__ mflag,
                                                    const unsigned char* __restrict__ pos8,
                                                    const int* __restrict__ pos32,
                                                    int use8,
                                                    const void* __restrict__ relv,
                                                    const int* __restrict__ flags,
                                                    unsigned short* __restrict__ ctxo) {
    extern __shared__ char smem[];
    const int f32u = flags[0];
    // grid: 2048 blocks = 32 bh x 64 i-tiles(16 rows); XCD swizzle (bijective 8x256)
    const int lin = blockIdx.y * 16 + blockIdx.x;
    const int logi = (lin & 7) * 256 + (lin >> 3);
    const int bh = logi >> 6, b = bh >> 4, h = bh & 15;
    const int i0 = (logi & 63) * 16;
    const int t = threadIdx.x;
    const int w = t >> 6, lane = t & 63;
    const int lm = lane & 15, lg = lane >> 4;
    const int dbase = w * 16;           // PV/epilogue d-slice per wave

    unsigned int* agU = (unsigned int*)(smem + AG_OFF);
    unsigned short* c2pS = (unsigned short*)(smem + C2P_OFF);
    unsigned short* rvS = (unsigned short*)(smem + RV_OFF);
    unsigned char* mfS = (unsigned char*)(smem + MF_OFF);

    for (int idx = t; idx < 16 * 33; idx += 256) {
        int il = idx / 33, k = idx % 33;
        c2pS[il * 34 + k] = c2p[(bh * S_ + i0 + il) * K_ + k];
    }
    for (int idx = t; idx < 33 * 64; idx += 256) {
        int k = idx >> 6, d = idx & 63;
        rvS[k * 64 + d] = f2b(ldf(relv, (h * K_ + k) * DH + d, f32u));
    }
    for (int idx = t; idx < 1024; idx += 256)
        mfS[idx] = (mflag[b * S_ + idx] != 0.f) ? 1 : 0;
    for (int idx = t; idx < 16 * 34; idx += 256) agU[idx] = 0u;

    // Q frags: 16 rows (lm), k = lg*8 (+32)
    bf16x8 aq0 = *(const bf16x8*)&qws[(bh * S_ + i0 + lm) * DH + lg * 8];
    bf16x8 aq1 = *(const bf16x8*)&qws[(bh * S_ + i0 + lm) * DH + 32 + lg * 8];
    f32x4 acc0 = {};

    const int p2cbase = bh * K_ * S_;
    const int rowbase = (b * S_ + i0 + lg * 4) * S_;
    __syncthreads();

    for (int c = 0; c < 16; ++c) {
        // ---- stage p2c strip [33][64] for this chunk (VT region free here) ----
        for (int idx = t; idx < 33 * 8; idx += 256) {
            int k = idx >> 3, v8 = idx & 7;
            uint4 src = *(const uint4*)&p2c[p2cbase + k * S_ + c * 64 + v8 * 8];
            unsigned int* dst = (unsigned int*)(smem + P2CS_OFF + k * 132 + v8 * 16);
            dst[0] = src.x; dst[1] = src.y; dst[2] = src.z; dst[3] = src.w;
        }
        __syncthreads();

        // ---- QK^T + fused gather/exp2 epilogue (wave w: cols w*16..w*16+15) ----
        {
            const int jc = w * 16 + lm;              // chunk-local col 0..63
            const int jcol = c * 64 + jc;            // global col
            int pb4[4];
            if (use8) {
#pragma unroll
                for (int r = 0; r < 4; ++r)
                    pb4[r] = pos8[rowbase + r * S_ + jcol];
            } else {
#pragma unroll
                for (int r = 0; r < 4; ++r) {
                    int p = pos32[rowbase + r * S_ + jcol];
                    pb4[r] = min(max(p, 0), K_ - 1);
                }
            }
            bf16x8 kf0 = *(const bf16x8*)&kws[(bh * S_ + jcol) * DH + lg * 8];
            bf16x8 kf1 = *(const bf16x8*)&kws[(bh * S_ + jcol) * DH + 32 + lg * 8];
            f32x4 a = {};
            a = __builtin_amdgcn_mfma_f32_16x16x32_bf16(aq0, kf0, a, 0, 0, 0);
            a = __builtin_amdgcn_mfma_f32_16x16x32_bf16(aq1, kf1, a, 0, 0, 0);
            const int masked = mfS[jcol];
#pragma unroll
            for (int r = 0; r < 4; ++r) {
                int il = lg * 4 + r;
                int pb = pb4[r];
                float gv = b2f(*(const unsigned short*)(smem + P2CS_OFF + pb * 132 + jc * 2));
                float s = a[r] * SCALEL + gv + b2f(c2pS[il * 34 + pb]);
                float ev = masked ? 0.f : exp2f(s);
                *(unsigned short*)(smem + ps_addr(il, jc)) = f2b(ev);
                atomicAdd(&agU[il * 34 + pb], (unsigned int)(ev * FXS));
            }
        }
        __syncthreads();

        // ---- stage V^T for this 64-j chunk (overwrites p2cS region) ----
#pragma unroll
        for (int u = 0; u < 2; ++u) {
            int idx = t + u * 256;          // 0..511 = 64 jj x 8 d-groups
            int jj = idx >> 3;
            int a8 = idx & 7;
            int d0 = a8 * 8;
            int j = c * 64 + jj;
            bf16x8 vv = *(const bf16x8*)&vws[(bh * S_ + j) * DH + d0];
#pragma unroll
            for (int e = 0; e < 8; ++e) {
                int ee = (e + a8) & 7;
                *(unsigned short*)(smem + VT_OFF + (d0 + ee) * 144 + jj * 2) =
                    ((short*)&vv)[ee];
            }
        }
        __syncthreads();

        // ---- PV over the 64-j chunk (wave w: d-slice w*16) ----
#pragma unroll
        for (int ks = 0; ks < 2; ++ks) {
            int jcb = ks * 32 + lg * 8;
            bf16x8 af = *(const bf16x8*)(smem + ps_addr(lm, jcb));
            bf16x8 b0 = *(const bf16x8*)(smem + VT_OFF + (dbase + lm) * 144 +
                                         (ks * 32 + lg * 8) * 2);
            acc0 = __builtin_amdgcn_mfma_f32_16x16x32_bf16(af, b0, acc0, 0, 0, 0);
        }
        __syncthreads();
    }

    // ---- epilogue: rowsum = sum_k agg; + agg @ rel_v; normalize; write ----
#pragma unroll
    for (int r = 0; r < 4; ++r) {
        int il = lg * 4 + r;
        float rs = 0.f;
        float o0 = acc0[r];
        for (int kb = 0; kb < K_; ++kb) {
            float a = (float)agU[il * 34 + kb] * FXI;
            rs += a;
            o0 += a * b2f(rvS[kb * 64 + dbase + lm]);
        }
        ctxo[(b * S_ + i0 + il) * D_ + h * DH + dbase + lm] = f2b(o0 / rs);
    }
}

// ---------------- launcher ----------------
extern "C" void kernel_launch(void* const* d_in, const int* in_sizes, int n_in,
                              void* d_out, int out_size, void* d_ws, size_t ws_size,
                              hipStream_t stream) {
    const void* hidden = d_in[0];
    const void* pos = d_in[1];
    const void* mask = d_in[2];
    const void* Wq = d_in[3];
    const void* bq = d_in[4];
    const void* Wk = d_in[5];
    const void* bk = d_in[6];
    const void* Wv = d_in[7];
    const void* bv = d_in[8];
    const void* Wo = d_in[9];
    const void* bo = d_in[10];
    const void* rq = d_in[11];
    const void* rk = d_in[12];
    const void* rv = d_in[13];

    unsigned char* wsb = (unsigned char*)d_ws;
    size_t o = 0;
    int* flags = (int*)(wsb + o);            o += 256;
    float* mfl = (float*)(wsb + o);          o += 2048 * 4;
    o = (o + 255) & ~(size_t)255;
    unsigned short* qb   = (unsigned short*)(wsb + o); o += 4194304;
    unsigned short* kb   = (unsigned short*)(wsb + o); o += 4194304;
    unsigned short* vb   = (unsigned short*)(wsb + o); o += 4194304;
    unsigned short* p2cb = (unsigned short*)(wsb + o); o += 2162688;
    unsigned short* c2pb = (unsigned short*)(wsb + o); o += 2162688;
    unsigned short* ctxb = (unsigned short*)(wsb + o); o += 4194304;
    unsigned char* pos8  = (unsigned char*)(wsb + o);  o += 2097152;
    const int use8 = (ws_size >= o) ? 1 : 0;
    unsigned short* wTq = (unsigned short*)(wsb + o);  o += 2097152;
    unsigned short* wTk = (unsigned short*)(wsb + o);  o += 2097152;
    unsigned short* wTv = (unsigned short*)(wsb + o);  o += 2097152;
    unsigned short* wTo = (unsigned short*)(wsb + o);  o += 2097152;  // ~31.6 MB total
    const int useT = (ws_size >= o) ? 1 : 0;

    float* out = (float*)d_out;
    const int* posi = (const int*)pos;

    hipFuncSetAttribute(reinterpret_cast<const void*>(attn_mfma),
                        hipFuncAttributeMaxDynamicSharedMemorySize, ATTN_LDS);

    dim3 tb(256);
    if (use8 && useT) {
        setup_fused<<<dim3(3073), tb, 0, stream>>>(hidden, mask, posi, Wq, Wk, Wv, Wo,
                                                   flags, mfl, pos8, wTq, wTk, wTv, wTo);
    } else {
        prep<<<dim3(1), tb, 0, stream>>>(hidden, mask, flags, mfl);
        if (use8) pos_pack<<<dim3(2048), tb, 0, stream>>>(posi, pos8);
    }
    gemm_qkv_mfma<<<dim3(16, 16, 3), tb, 0, stream>>>(hidden, Wq, Wk, Wv,
                                                      wTq, wTk, wTv,
                                                      bq, bk, bv, flags, useT,
                                                      qb, kb, vb);
    rel_fused<<<dim3(16, 32, 2), tb, 0, stream>>>(kb, qb, rq, rk, flags, p2cb, c2pb);
    attn_mfma<<<dim3(16, 128), tb, ATTN_LDS, stream>>>(qb, kb, vb, p2cb, c2pb, mfl,
                                                       pos8, posi, use8, rv, flags,
                                                       ctxb);
    gemm_out_mfma<<<dim3(16, 16), tb, 0, stream>>>(ctxb, Wo, wTo, bo, flags, useT,
                                                   out);
}

// Round 21
// 151.005 us; speedup vs baseline: 1.2772x; 1.2772x over previous
//
#include <hip/hip_runtime.h>
#include <hip/hip_bf16.h>

#define B_ 2
#define S_ 1024
#define D_ 1024
#define H_ 16
#define K_ 33
#define DH 64
#define SCALE 0.07216878364870322f  // 1/sqrt(3*64)
#define LOG2E 1.4426950408889634f
#define SCALEL (SCALE * LOG2E)
#define FXS 32768.0f
#define FXI (1.0f / 32768.0f)

typedef __attribute__((ext_vector_type(8))) short bf16x8;
typedef __attribute__((ext_vector_type(4))) float f32x4;

// ---------- dtype helpers ----------
__device__ __forceinline__ float b2f(unsigned short u) {
    return __uint_as_float(((unsigned int)u) << 16);
}
__device__ __forceinline__ unsigned short f2b(float f) {  // RNE
    unsigned int u = __float_as_uint(f);
    u += 0x7FFFu + ((u >> 16) & 1u);
    return (unsigned short)(u >> 16);
}
__device__ __forceinline__ float ldf(const void* p, int i, int f32) {
    return f32 ? ((const float*)p)[i] : b2f(((const unsigned short*)p)[i]);
}
__device__ __forceinline__ float4 ldf4(const void* p, int i, int f32) {  // i % 4 == 0
    if (f32) return *(const float4*)((const float*)p + i);
    ushort4 u = *(const ushort4*)((const unsigned short*)p + i);
    return make_float4(b2f(u.x), b2f(u.y), b2f(u.z), b2f(u.w));
}
__device__ __forceinline__ float4 ldb4(const unsigned short* p, int i) {  // bf16 buffer
    ushort4 u = *(const ushort4*)(p + i);
    return make_float4(b2f(u.x), b2f(u.y), b2f(u.z), b2f(u.w));
}
__device__ __forceinline__ int sniff_f32(const void* hidden) {
    __shared__ int cnt;
    if (threadIdx.x == 0) cnt = 0;
    __syncthreads();
    const unsigned short* hu = (const unsigned short*)hidden;
    int c = 0;
    for (int i = threadIdx.x; i < 2048; i += 256) {
        int e = (hu[i] >> 7) & 0xFF;
        if (e >= 0x8E) c++;
    }
    if (c) atomicAdd(&cnt, c);
    __syncthreads();
    return (cnt >= 8) ? 1 : 0;
}

// ---------------- fused setup: pos_pack (blocks 0..2047), w_pack (2048..3071), prep (3072) ----------------
__global__ __launch_bounds__(256) void setup_fused(const void* __restrict__ hidden,
                                                   const void* __restrict__ mask,
                                                   const int* __restrict__ pos,
                                                   const void* __restrict__ W0,
                                                   const void* __restrict__ W1,
                                                   const void* __restrict__ W2,
                                                   const void* __restrict__ W3,
                                                   int* __restrict__ flags,
                                                   float* __restrict__ mflag,
                                                   unsigned char* __restrict__ pos8,
                                                   unsigned short* __restrict__ T0,
                                                   unsigned short* __restrict__ T1,
                                                   unsigned short* __restrict__ T2,
                                                   unsigned short* __restrict__ T3) {
    const int bid = blockIdx.x;
    const int t = threadIdx.x;
    if (bid < 2048) {
        int i = bid * 256 + t;
        if (i < (B_ * S_ * S_) / 4) {
            int4 p = *(const int4*)&pos[i * 4];
            uchar4 o;
            o.x = (unsigned char)min(max(p.x, 0), K_ - 1);
            o.y = (unsigned char)min(max(p.y, 0), K_ - 1);
            o.z = (unsigned char)min(max(p.z, 0), K_ - 1);
            o.w = (unsigned char)min(max(p.w, 0), K_ - 1);
            *(uchar4*)&pos8[i * 4] = o;
        }
        return;
    }
    if (bid < 3072) {
        const int f32u = sniff_f32(hidden);
        __shared__ unsigned short tl[64][66];
        int r = bid - 2048;
        int z = r >> 8;
        int wy = (r & 255) >> 4, wx = r & 15;
        const void* W = z == 0 ? W0 : (z == 1 ? W1 : (z == 2 ? W2 : W3));
        unsigned short* T = z == 0 ? T0 : (z == 1 ? T1 : (z == 2 ? T2 : T3));
        const int k0 = wy * 64, n0 = wx * 64;
        {
            int kr = t >> 2, nc = (t & 3) * 16;
#pragma unroll
            for (int u = 0; u < 4; ++u) {
                float4 v = ldf4(W, (k0 + kr) * 1024 + n0 + nc + u * 4, f32u);
                tl[kr][nc + u * 4 + 0] = f2b(v.x);
                tl[kr][nc + u * 4 + 1] = f2b(v.y);
                tl[kr][nc + u * 4 + 2] = f2b(v.z);
                tl[kr][nc + u * 4 + 3] = f2b(v.w);
            }
        }
        __syncthreads();
        {
            int nr = t >> 2, kc = (t & 3) * 16;
            unsigned short o[16];
#pragma unroll
            for (int u = 0; u < 16; ++u) o[u] = tl[kc + u][nr];
#pragma unroll
            for (int u = 0; u < 4; ++u)
                *(ushort4*)&T[(n0 + nr) * 1024 + k0 + kc + u * 4] = *(ushort4*)&o[u * 4];
        }
        return;
    }
    // ---- prep role ----
    {
        __shared__ int mev[6];
        const int f32u = sniff_f32(hidden);
        if (t < 6) mev[t] = 0;
        __syncthreads();
        const unsigned char* mb = (const unsigned char*)mask;
        int e_bf = 0, e_f32 = 0, e_f64 = 0, e_f16 = 0, e_u8 = 0;
        for (int p = t; p < 2048; p += 256) {
            unsigned char v = mb[p];
            if ((p & 7) == 6 && v == 0xF0) e_f64 = 1;
            if ((p & 3) == 1 && v == 0x3F) e_bf = 1;
            if ((p & 3) == 3 && v == 0x3F) e_f32 = 1;
            if ((p & 1) == 1 && v == 0x3C) e_f16 = 1;
            if ((p & 3) != 0 && v != 0) e_u8 = 1;
        }
        if (e_f64) atomicOr(&mev[5], 1);
        if (e_bf)  atomicOr(&mev[3], 1);
        if (e_f32) atomicOr(&mev[2], 1);
        if (e_f16) atomicOr(&mev[4], 1);
        if (e_u8)  atomicOr(&mev[1], 1);
        __syncthreads();
        const int mm = mev[5] ? 5 : (mev[3] ? 3 : (mev[2] ? 2 : (mev[4] ? 4 : (mev[1] ? 1 : 0))));
        if (t == 0) { flags[0] = f32u; flags[2] = mm; }
        for (int j = t; j < B_ * S_; j += 256) {
            int m;
            if (mm == 5)      m = (((const double*)mask)[j] != 0.0);
            else if (mm == 3 || mm == 4) m = (((const unsigned short*)mask)[j] != 0);
            else if (mm == 2) m = (((const float*)mask)[j] != 0.f);
            else if (mm == 1) m = (mb[j] != 0);
            else              m = (((const int*)mask)[j] != 0);
            mflag[j] = m ? 1.f : 0.f;
        }
    }
}

// ---------------- standalone fallbacks (small-ws path) ----------------
__global__ __launch_bounds__(256) void prep(const void* __restrict__ hidden,
                                            const void* __restrict__ mask,
                                            int* __restrict__ flags,
                                            float* __restrict__ mflag) {
    __shared__ int mev[6];
    const int t = threadIdx.x;
    const int f32u = sniff_f32(hidden);
    if (t < 6) mev[t] = 0;
    __syncthreads();
    const unsigned char* mb = (const unsigned char*)mask;
    int e_bf = 0, e_f32 = 0, e_f64 = 0, e_f16 = 0, e_u8 = 0;
    for (int p = t; p < 2048; p += 256) {
        unsigned char v = mb[p];
        if ((p & 7) == 6 && v == 0xF0) e_f64 = 1;
        if ((p & 3) == 1 && v == 0x3F) e_bf = 1;
        if ((p & 3) == 3 && v == 0x3F) e_f32 = 1;
        if ((p & 1) == 1 && v == 0x3C) e_f16 = 1;
        if ((p & 3) != 0 && v != 0) e_u8 = 1;
    }
    if (e_f64) atomicOr(&mev[5], 1);
    if (e_bf)  atomicOr(&mev[3], 1);
    if (e_f32) atomicOr(&mev[2], 1);
    if (e_f16) atomicOr(&mev[4], 1);
    if (e_u8)  atomicOr(&mev[1], 1);
    __syncthreads();
    const int mm = mev[5] ? 5 : (mev[3] ? 3 : (mev[2] ? 2 : (mev[4] ? 4 : (mev[1] ? 1 : 0))));
    if (t == 0) { flags[0] = f32u; flags[2] = mm; }
    for (int j = t; j < B_ * S_; j += 256) {
        int m;
        if (mm == 5)      m = (((const double*)mask)[j] != 0.0);
        else if (mm == 3 || mm == 4) m = (((const unsigned short*)mask)[j] != 0);
        else if (mm == 2) m = (((const float*)mask)[j] != 0.f);
        else if (mm == 1) m = (mb[j] != 0);
        else              m = (((const int*)mask)[j] != 0);
        mflag[j] = m ? 1.f : 0.f;
    }
}

__global__ __launch_bounds__(256) void pos_pack(const int* __restrict__ pos,
                                                unsigned char* __restrict__ pos8) {
    int i = blockIdx.x * 256 + threadIdx.x;
    if (i >= (B_ * S_ * S_) / 4) return;
    int4 p = *(const int4*)&pos[i * 4];
    uchar4 o;
    o.x = (unsigned char)min(max(p.x, 0), K_ - 1);
    o.y = (unsigned char)min(max(p.y, 0), K_ - 1);
    o.z = (unsigned char)min(max(p.z, 0), K_ - 1);
    o.w = (unsigned char)min(max(p.w, 0), K_ - 1);
    *(uchar4*)&pos8[i * 4] = o;
}

// ---------------- MFMA GEMM v5: 128x64 tile, 256 thr = 4 waves, BK=32, reg-prefetch ----------------
__global__ __launch_bounds__(256, 3) void gemm_qkv_mfma(const void* __restrict__ X,
                                                        const void* __restrict__ W0,
                                                        const void* __restrict__ W1,
                                                        const void* __restrict__ W2,
                                                        const unsigned short* __restrict__ T0,
                                                        const unsigned short* __restrict__ T1,
                                                        const unsigned short* __restrict__ T2,
                                                        const void* __restrict__ b0,
                                                        const void* __restrict__ b1,
                                                        const void* __restrict__ b2,
                                                        const int* __restrict__ flags, int useT,
                                                        unsigned short* __restrict__ q,
                                                        unsigned short* __restrict__ kk_,
                                                        unsigned short* __restrict__ v) {
    __shared__ unsigned short Asl[128][40];
    __shared__ unsigned short Bsl[64][40];
    const int f32u = flags[0];
    const int z = blockIdx.z;
    const void* W = z == 0 ? W0 : (z == 1 ? W1 : W2);
    const unsigned short* WT = z == 0 ? T0 : (z == 1 ? T1 : T2);
    const void* bias = z == 0 ? b0 : (z == 1 ? b1 : b2);
    unsigned short* outp = z == 0 ? q : (z == 1 ? kk_ : v);
    const int m0 = blockIdx.y * 128, n0 = blockIdx.x * 64;
    const int t = threadIdx.x;
    const int w = t >> 6, lane = t & 63;
    const int wr = w >> 1, wc = w & 1;
    const int lm = lane & 15, lg = lane >> 4;

    const int am = t >> 1, ac16 = (t & 1) * 16;
    const int bn = t >> 2, bk8 = (t & 3) * 8;
    const int fbn = t & 63, fbkq = (t >> 6) * 8;

    f32x4 acc[4][2] = {};
    float4 pa[4];
    ushort4 tb0, tb1;
    float pbx[8];

    {
        int base = (m0 + am) * 1024 + ac16;
#pragma unroll
        for (int u = 0; u < 4; ++u) pa[u] = ldf4(X, base + u * 4, f32u);
        if (useT) {
            const ushort4* s = (const ushort4*)&WT[(n0 + bn) * 1024 + bk8];
            tb0 = s[0]; tb1 = s[1];
        } else {
#pragma unroll
            for (int qi = 0; qi < 8; ++qi)
                pbx[qi] = ldf(W, (fbkq + qi) * 1024 + n0 + fbn, f32u);
        }
    }

    for (int k0 = 0; k0 < 1024; k0 += 32) {
        {
#pragma unroll
            for (int u = 0; u < 4; ++u) {
                ushort4 uv = {f2b(pa[u].x), f2b(pa[u].y), f2b(pa[u].z), f2b(pa[u].w)};
                *(ushort4*)&Asl[am][ac16 + u * 4] = uv;
            }
            if (useT) {
                *(ushort4*)&Bsl[bn][bk8] = tb0;
                *(ushort4*)&Bsl[bn][bk8 + 4] = tb1;
            } else {
#pragma unroll
                for (int qi = 0; qi < 8; qi += 2) {
                    unsigned int pk = (unsigned int)f2b(pbx[qi]) |
                                      ((unsigned int)f2b(pbx[qi + 1]) << 16);
                    *(unsigned int*)&Bsl[fbn][fbkq + qi] = pk;
                }
            }
        }
        __syncthreads();
        if (k0 + 32 < 1024) {
            int kn = k0 + 32;
            int base = (m0 + am) * 1024 + kn + ac16;
#pragma unroll
            for (int u = 0; u < 4; ++u) pa[u] = ldf4(X, base + u * 4, f32u);
            if (useT) {
                const ushort4* s = (const ushort4*)&WT[(n0 + bn) * 1024 + kn + bk8];
                tb0 = s[0]; tb1 = s[1];
            } else {
#pragma unroll
                for (int qi = 0; qi < 8; ++qi)
                    pbx[qi] = ldf(W, (kn + fbkq + qi) * 1024 + n0 + fbn, f32u);
            }
        }
        bf16x8 af[4], bfr[2];
#pragma unroll
        for (int mi = 0; mi < 4; ++mi)
            af[mi] = *(const bf16x8*)&Asl[wr * 64 + mi * 16 + lm][lg * 8];
#pragma unroll
        for (int nj = 0; nj < 2; ++nj)
            bfr[nj] = *(const bf16x8*)&Bsl[wc * 32 + nj * 16 + lm][lg * 8];
#pragma unroll
        for (int mi = 0; mi < 4; ++mi)
#pragma unroll
            for (int nj = 0; nj < 2; ++nj)
                acc[mi][nj] = __builtin_amdgcn_mfma_f32_16x16x32_bf16(af[mi], bfr[nj],
                                                                      acc[mi][nj], 0, 0, 0);
        __syncthreads();
    }
#pragma unroll
    for (int nj = 0; nj < 2; ++nj) {
        int n = n0 + wc * 32 + nj * 16 + lm;
        float bv = ldf(bias, n, f32u);
        int hh = n >> 6, dd = n & 63;
#pragma unroll
        for (int mi = 0; mi < 4; ++mi) {
#pragma unroll
            for (int r = 0; r < 4; ++r) {
                int m = m0 + wr * 64 + mi * 16 + lg * 4 + r;
                int bb = m >> 10, ii = m & 1023;
                outp[((bb * H_ + hh) * S_ + ii) * DH + dd] = f2b(acc[mi][nj][r] + bv);
            }
        }
    }
}

// ---------------- MFMA GEMM v5: ctx(bf16) @ Wo + bo -> f32 d_out, 128x64 tile ----------------
__global__ __launch_bounds__(256, 3) void gemm_out_mfma(const unsigned short* __restrict__ X,
                                                        const void* __restrict__ W,
                                                        const unsigned short* __restrict__ WT,
                                                        const void* __restrict__ bias,
                                                        const int* __restrict__ flags, int useT,
                                                        float* __restrict__ out) {
    __shared__ unsigned short Asl[128][40];
    __shared__ unsigned short Bsl[64][40];
    const int f32u = flags[0];
    const int m0 = blockIdx.y * 128, n0 = blockIdx.x * 64;
    const int t = threadIdx.x;
    const int w = t >> 6, lane = t & 63;
    const int wr = w >> 1, wc = w & 1;
    const int lm = lane & 15, lg = lane >> 4;

    const int am = t >> 1, ac16 = (t & 1) * 16;
    const int bn = t >> 2, bk8 = (t & 3) * 8;
    const int fbn = t & 63, fbkq = (t >> 6) * 8;

    f32x4 acc[4][2] = {};
    ushort4 pa[4];
    ushort4 tb0, tb1;
    float pbx[8];

    {
        const ushort4* src = (const ushort4*)&X[(m0 + am) * 1024 + ac16];
#pragma unroll
        for (int u = 0; u < 4; ++u) pa[u] = src[u];
        if (useT) {
            const ushort4* s = (const ushort4*)&WT[(n0 + bn) * 1024 + bk8];
            tb0 = s[0]; tb1 = s[1];
        } else {
#pragma unroll
            for (int qi = 0; qi < 8; ++qi)
                pbx[qi] = ldf(W, (fbkq + qi) * 1024 + n0 + fbn, f32u);
        }
    }

    for (int k0 = 0; k0 < 1024; k0 += 32) {
        {
#pragma unroll
            for (int u = 0; u < 4; ++u) *(ushort4*)&Asl[am][ac16 + u * 4] = pa[u];
            if (useT) {
                *(ushort4*)&Bsl[bn][bk8] = tb0;
                *(ushort4*)&Bsl[bn][bk8 + 4] = tb1;
            } else {
#pragma unroll
                for (int qi = 0; qi < 8; qi += 2) {
                    unsigned int pk = (unsigned int)f2b(pbx[qi]) |
                                      ((unsigned int)f2b(pbx[qi + 1]) << 16);
                    *(unsigned int*)&Bsl[fbn][fbkq + qi] = pk;
                }
            }
        }
        __syncthreads();
        if (k0 + 32 < 1024) {
            int kn = k0 + 32;
            const ushort4* src = (const ushort4*)&X[(m0 + am) * 1024 + kn + ac16];
#pragma unroll
            for (int u = 0; u < 4; ++u) pa[u] = src[u];
            if (useT) {
                const ushort4* s = (const ushort4*)&WT[(n0 + bn) * 1024 + kn + bk8];
                tb0 = s[0]; tb1 = s[1];
            } else {
#pragma unroll
                for (int qi = 0; qi < 8; ++qi)
                    pbx[qi] = ldf(W, (kn + fbkq + qi) * 1024 + n0 + fbn, f32u);
            }
        }
        bf16x8 af[4], bfr[2];
#pragma unroll
        for (int mi = 0; mi < 4; ++mi)
            af[mi] = *(const bf16x8*)&Asl[wr * 64 + mi * 16 + lm][lg * 8];
#pragma unroll
        for (int nj = 0; nj < 2; ++nj)
            bfr[nj] = *(const bf16x8*)&Bsl[wc * 32 + nj * 16 + lm][lg * 8];
#pragma unroll
        for (int mi = 0; mi < 4; ++mi)
#pragma unroll
            for (int nj = 0; nj < 2; ++nj)
                acc[mi][nj] = __builtin_amdgcn_mfma_f32_16x16x32_bf16(af[mi], bfr[nj],
                                                                      acc[mi][nj], 0, 0, 0);
        __syncthreads();
    }
#pragma unroll
    for (int nj = 0; nj < 2; ++nj) {
        int n = n0 + wc * 32 + nj * 16 + lm;
        float bv = ldf(bias, n, f32u);
#pragma unroll
        for (int mi = 0; mi < 4; ++mi) {
#pragma unroll
            for (int r = 0; r < 4; ++r) {
                int m = m0 + wr * 64 + mi * 16 + lg * 4 + r;
                out[m * 1024 + n] = acc[mi][nj][r] + bv;
            }
        }
    }
}

// ---------------- fused rel kernels: z=0 -> p2c, z=1 -> c2p (outputs pre-scaled by log2e) ----------------
__global__ __launch_bounds__(256) void rel_fused(const unsigned short* __restrict__ kws,
                                                 const unsigned short* __restrict__ qws,
                                                 const void* __restrict__ relq,
                                                 const void* __restrict__ relk,
                                                 const int* __restrict__ flags,
                                                 unsigned short* __restrict__ p2c,
                                                 unsigned short* __restrict__ c2p) {
    __shared__ float xt[64][68];
    __shared__ float rr[33][68];
    const int f32u = flags[0];
    const int bh = blockIdx.y, h = bh & 15;
    const int x0 = blockIdx.x * 64;
    const int t = threadIdx.x;
    if (blockIdx.z == 0) {
#pragma unroll
        for (int qq = 0; qq < 4; ++qq) {
            int idx = t + 256 * qq;
            int j = idx >> 4, d4 = idx & 15;
            *(float4*)&xt[j][d4 * 4] = ldb4(kws, (bh * S_ + x0 + j) * DH + d4 * 4);
        }
        for (int idx = t; idx < 33 * 16; idx += 256) {
            int k = idx >> 4, d4 = idx & 15;
            *(float4*)&rr[k][d4 * 4] = ldf4(relq, (h * K_ + k) * DH + d4 * 4, f32u);
        }
        __syncthreads();
        for (int o = t; o < 33 * 64; o += 256) {
            int k = o >> 6, j = o & 63;
            float s = 0.f;
#pragma unroll
            for (int d4 = 0; d4 < 16; ++d4) {
                float4 a = *(const float4*)&rr[k][d4 * 4];
                float4 b = *(const float4*)&xt[j][d4 * 4];
                s += a.x * b.x + a.y * b.y + a.z * b.z + a.w * b.w;
            }
            p2c[(bh * K_ + k) * S_ + x0 + j] = f2b(s * SCALEL);
        }
    } else {
#pragma unroll
        for (int qq = 0; qq < 4; ++qq) {
            int idx = t + 256 * qq;
            int i = idx >> 4, d4 = idx & 15;
            *(float4*)&xt[i][d4 * 4] = ldb4(qws, (bh * S_ + x0 + i) * DH + d4 * 4);
        }
        for (int idx = t; idx < 33 * 16; idx += 256) {
            int k = idx >> 4, d4 = idx & 15;
            *(float4*)&rr[k][d4 * 4] = ldf4(relk, (h * K_ + k) * DH + d4 * 4, f32u);
        }
        __syncthreads();
        for (int o = t; o < 64 * 33; o += 256) {
            int i = o / 33, k = o % 33;
            float s = 0.f;
#pragma unroll
            for (int d4 = 0; d4 < 16; ++d4) {
                float4 a = *(const float4*)&xt[i][d4 * 4];
                float4 b = *(const float4*)&rr[k][d4 * 4];
                s += a.x * b.x + a.y * b.y + a.z * b.z + a.w * b.w;
            }
            c2p[(bh * S_ + x0 + i) * K_ + k] = f2b(s * SCALEL);
        }
    }
}

// ---------------- MFMA attention v11: 128-col chunks -> 52.1 KB LDS ----------------
#define PS_OFF   0            // Ps [64][128] bf16 swizzled, pitch 256B (16384)
#define VT_OFF   16384        // V^T chunk staging, pitch 272B (17408)
#define P2CS_OFF 16384        // p2c strip [33][128] bf16, pitch 260B (shares VT region)
#define C2P_OFF  33792        // [64][34] bf16 (4352)
#define AG_OFF   38144        // [64][34] u32 (8704)
#define RV_OFF   46848        // [33][64] bf16 (4224)
#define MF_OFF   51072        // u8[1024]
#define ATTN_LDS 52096

__device__ __forceinline__ int ps_addr(int il, int jc) {  // jc in 0..127
    return PS_OFF + il * 256 +
           ((jc * 2) ^ ((((il >> 2) & 3) << 5) ^ ((il & 3) << 4)));
}

__global__ __launch_bounds__(512, 4) void attn_mfma(const unsigned short* __restrict__ qws,
                                                    const unsigned short* __restrict__ kws,
                                                    const unsigned short* __restrict__ vws,
                                                    const unsigned short* __restrict__ p2c,
                                                    const unsigned short* __restrict__ c2p,
                                                    const float* __restrict__ mflag,
                                                    const unsigned char* __restrict__ pos8,
                                                    const int* __restrict__ pos32,
                                                    int use8,
                                                    const void* __restrict__ relv,
                                                    const int* __restrict__ flags,
                                                    unsigned short* __restrict__ ctxo) {
    extern __shared__ char smem[];
    const int f32u = flags[0];
    const int lin = blockIdx.y * 16 + blockIdx.x;
    const int logi = (lin & 7) * 64 + (lin >> 3);
    const int bh = logi >> 4, b = bh >> 4, h = bh & 15;
    const int i0 = (logi & 15) * 64;
    const int t = threadIdx.x;
    const int w = t >> 6, lane = t & 63;
    const int lm = lane & 15, lg = lane >> 4;
    const int iband = (w & 3) * 16;
    const int jh = w >> 2;              // wave's 64-col half of the 128-col chunk
    const int dbase = jh * 32;

    unsigned int* agU = (unsigned int*)(smem + AG_OFF);
    unsigned short* c2pS = (unsigned short*)(smem + C2P_OFF);
    unsigned short* rvS = (unsigned short*)(smem + RV_OFF);
    unsigned char* mfS = (unsigned char*)(smem + MF_OFF);

    for (int idx = t; idx < 64 * 33; idx += 512) {
        int il = idx / 33, k = idx % 33;
        c2pS[il * 34 + k] = c2p[(bh * S_ + i0 + il) * K_ + k];
    }
    for (int idx = t; idx < 33 * 64; idx += 512) {
        int k = idx >> 6, d = idx & 63;
        rvS[k * 64 + d] = f2b(ldf(relv, (h * K_ + k) * DH + d, f32u));
    }
    for (int idx = t; idx < 1024; idx += 512)
        mfS[idx] = (mflag[b * S_ + idx] != 0.f) ? 1 : 0;
    for (int idx = t; idx < 64 * 34; idx += 512) agU[idx] = 0u;

    bf16x8 aq0 = *(const bf16x8*)&qws[(bh * S_ + i0 + iband + lm) * DH + lg * 8];
    bf16x8 aq1 = *(const bf16x8*)&qws[(bh * S_ + i0 + iband + lm) * DH + 32 + lg * 8];
    f32x4 acc0 = {}, acc1 = {};

    const int p2cbase = bh * K_ * S_;
    const int rowbase = (b * S_ + i0 + iband + lg * 4) * S_;
    __syncthreads();

    for (int c = 0; c < 8; ++c) {
        // ---- stage p2c strip [33][128] for this chunk (VT region free here) ----
        for (int idx = t; idx < 33 * 16; idx += 512) {
            int k = idx >> 4, v8 = idx & 15;
            uint4 src = *(const uint4*)&p2c[p2cbase + k * S_ + c * 128 + v8 * 8];
            unsigned int* dst = (unsigned int*)(smem + P2CS_OFF + k * 260 + v8 * 16);
            dst[0] = src.x; dst[1] = src.y; dst[2] = src.z; dst[3] = src.w;
        }
        __syncthreads();

        // ---- QK^T + fused gather/exp2 epilogue ----
        for (int jt = 0; jt < 4; ++jt) {
            const int jc = jh * 64 + jt * 16 + lm;   // chunk-local col 0..127
            const int jcol = c * 128 + jc;           // global col
            int pb4[4];
            if (use8) {
#pragma unroll
                for (int r = 0; r < 4; ++r)
                    pb4[r] = pos8[rowbase + r * S_ + jcol];
            } else {
#pragma unroll
                for (int r = 0; r < 4; ++r) {
                    int p = pos32[rowbase + r * S_ + jcol];
                    pb4[r] = min(max(p, 0), K_ - 1);
                }
            }
            bf16x8 kf0 = *(const bf16x8*)&kws[(bh * S_ + jcol) * DH + lg * 8];
            bf16x8 kf1 = *(const bf16x8*)&kws[(bh * S_ + jcol) * DH + 32 + lg * 8];
            f32x4 a = {};
            a = __builtin_amdgcn_mfma_f32_16x16x32_bf16(aq0, kf0, a, 0, 0, 0);
            a = __builtin_amdgcn_mfma_f32_16x16x32_bf16(aq1, kf1, a, 0, 0, 0);
            const int masked = mfS[jcol];
#pragma unroll
            for (int r = 0; r < 4; ++r) {
                int il = iband + lg * 4 + r;
                int pb = pb4[r];
                float gv = b2f(*(const unsigned short*)(smem + P2CS_OFF + pb * 260 + jc * 2));
                float s = a[r] * SCALEL + gv + b2f(c2pS[il * 34 + pb]);
                float ev = masked ? 0.f : exp2f(s);
                *(unsigned short*)(smem + ps_addr(il, jc)) = f2b(ev);
                atomicAdd(&agU[il * 34 + pb], (unsigned int)(ev * FXS));
            }
        }
        __syncthreads();

        // ---- stage V^T for this 128-j chunk (overwrites p2cS region) ----
#pragma unroll
        for (int u = 0; u < 2; ++u) {
            int idx = t + u * 512;          // 0..1023 = 128 jj x 8 d-groups
            int jj = idx >> 3;
            int a8 = idx & 7;
            int d0 = a8 * 8;
            int j = c * 128 + jj;
            bf16x8 vv = *(const bf16x8*)&vws[(bh * S_ + j) * DH + d0];
#pragma unroll
            for (int e = 0; e < 8; ++e) {
                int ee = (e + a8) & 7;
                *(unsigned short*)(smem + VT_OFF + (d0 + ee) * 272 + jj * 2) =
                    ((short*)&vv)[ee];
            }
        }
        __syncthreads();

        // ---- PV over the 128-j chunk ----
#pragma unroll
        for (int ks = 0; ks < 4; ++ks) {
            int jcb = ks * 32 + lg * 8;
            bf16x8 af = *(const bf16x8*)(smem + ps_addr(iband + lm, jcb));
            bf16x8 b0 = *(const bf16x8*)(smem + VT_OFF + (dbase + lm) * 272 +
                                         (ks * 32 + lg * 8) * 2);
            bf16x8 b1 = *(const bf16x8*)(smem + VT_OFF + (dbase + 16 + lm) * 272 +
                                         (ks * 32 + lg * 8) * 2);
            acc0 = __builtin_amdgcn_mfma_f32_16x16x32_bf16(af, b0, acc0, 0, 0, 0);
            acc1 = __builtin_amdgcn_mfma_f32_16x16x32_bf16(af, b1, acc1, 0, 0, 0);
        }
        __syncthreads();
    }

    // ---- epilogue ----
#pragma unroll
    for (int r = 0; r < 4; ++r) {
        int il = iband + lg * 4 + r;
        float rs = 0.f;
        float o0 = acc0[r], o1 = acc1[r];
        for (int kb = 0; kb < K_; ++kb) {
            float a = (float)agU[il * 34 + kb] * FXI;
            rs += a;
            o0 += a * b2f(rvS[kb * 64 + dbase + lm]);
            o1 += a * b2f(rvS[kb * 64 + dbase + 16 + lm]);
        }
        float inv = 1.0f / rs;
        ctxo[(b * S_ + i0 + il) * D_ + h * DH + dbase + lm] = f2b(o0 * inv);
        ctxo[(b * S_ + i0 + il) * D_ + h * DH + dbase + 16 + lm] = f2b(o1 * inv);
    }
}

// ---------------- launcher ----------------
extern "C" void kernel_launch(void* const* d_in, const int* in_sizes, int n_in,
                              void* d_out, int out_size, void* d_ws, size_t ws_size,
                              hipStream_t stream) {
    const void* hidden = d_in[0];
    const void* pos = d_in[1];
    const void* mask = d_in[2];
    const void* Wq = d_in[3];
    const void* bq = d_in[4];
    const void* Wk = d_in[5];
    const void* bk = d_in[6];
    const void* Wv = d_in[7];
    const void* bv = d_in[8];
    const void* Wo = d_in[9];
    const void* bo = d_in[10];
    const void* rq = d_in[11];
    const void* rk = d_in[12];
    const void* rv = d_in[13];

    unsigned char* wsb = (unsigned char*)d_ws;
    size_t o = 0;
    int* flags = (int*)(wsb + o);            o += 256;
    float* mfl = (float*)(wsb + o);          o += 2048 * 4;
    o = (o + 255) & ~(size_t)255;
    unsigned short* qb   = (unsigned short*)(wsb + o); o += 4194304;
    unsigned short* kb   = (unsigned short*)(wsb + o); o += 4194304;
    unsigned short* vb   = (unsigned short*)(wsb + o); o += 4194304;
    unsigned short* p2cb = (unsigned short*)(wsb + o); o += 2162688;
    unsigned short* c2pb = (unsigned short*)(wsb + o); o += 2162688;
    unsigned short* ctxb = (unsigned short*)(wsb + o); o += 4194304;
    unsigned char* pos8  = (unsigned char*)(wsb + o);  o += 2097152;
    const int use8 = (ws_size >= o) ? 1 : 0;
    unsigned short* wTq = (unsigned short*)(wsb + o);  o += 2097152;
    unsigned short* wTk = (unsigned short*)(wsb + o);  o += 2097152;
    unsigned short* wTv = (unsigned short*)(wsb + o);  o += 2097152;
    unsigned short* wTo = (unsigned short*)(wsb + o);  o += 2097152;  // ~31.6 MB total
    const int useT = (ws_size >= o) ? 1 : 0;

    float* out = (float*)d_out;
    const int* posi = (const int*)pos;

    hipFuncSetAttribute(reinterpret_cast<const void*>(attn_mfma),
                        hipFuncAttributeMaxDynamicSharedMemorySize, ATTN_LDS);

    dim3 tb(256);
    if (use8 && useT) {
        setup_fused<<<dim3(3073), tb, 0, stream>>>(hidden, mask, posi, Wq, Wk, Wv, Wo,
                                                   flags, mfl, pos8, wTq, wTk, wTv, wTo);
    } else {
        prep<<<dim3(1), tb, 0, stream>>>(hidden, mask, flags, mfl);
        if (use8) pos_pack<<<dim3(2048), tb, 0, stream>>>(posi, pos8);
    }
    gemm_qkv_mfma<<<dim3(16, 16, 3), tb, 0, stream>>>(hidden, Wq, Wk, Wv,
                                                      wTq, wTk, wTv,
                                                      bq, bk, bv, flags, useT,
                                                      qb, kb, vb);
    rel_fused<<<dim3(16, 32, 2), tb, 0, stream>>>(kb, qb, rq, rk, flags, p2cb, c2pb);
    attn_mfma<<<dim3(16, 32), dim3(512), ATTN_LDS, stream>>>(qb, kb, vb, p2cb, c2pb, mfl,
                                                             pos8, posi, use8, rv, flags,
                                                             ctxb);
    gemm_out_mfma<<<dim3(16, 16), tb, 0, stream>>>(ctxb, Wo, wTo, bo, flags, useT,
                                                   out);
}